// Round 6
// baseline (164.457 us; speedup 1.0000x reference)
//
#include <hip/hip_runtime.h>
#include <math.h>

typedef __attribute__((ext_vector_type(8))) short b8;
typedef __attribute__((ext_vector_type(4))) float f4;
typedef float f4u __attribute__((ext_vector_type(4), aligned(4)));
typedef _Float16 h8 __attribute__((ext_vector_type(8)));
typedef _Float16 h2 __attribute__((ext_vector_type(2)));

// ---------------- ws layout (float offsets) --------------------------------
#define XT2   0                     // f16[4*4096*256] = 2097152 floats
#define OF2   2097152               // q=0 partial slice (294912 fp32)
#define WH2   2392064               // bf16-split offset-conv weights (hi)
#define WL2   2428928               // (lo)
#define OFPG  2465792               // q=1 partial slice (294912 fp32)
#define AF2   3571712               // f16[589824] main A-frags
#define BF2   3866624               // 256 folded bias

// Raw barrier: drain LDS only, leave register-destined global loads in
// flight across the barrier.
#define BARRIER_RELAX() do {                                   \
    asm volatile("s_waitcnt lgkmcnt(0)" ::: "memory");         \
    __builtin_amdgcn_s_barrier();                              \
  } while (0)

__device__ inline ushort f2bf(float f) {
  uint u = __float_as_uint(f);
  return (ushort)((u + 0x7FFFu + ((u >> 16) & 1u)) >> 16);
}
__device__ inline h2 u2h2(uint u) { union { uint u; h2 h; } x; x.u = u; return x.h; }
__device__ inline uint h22u(h2 h) { union { uint u; h2 h; } x; x.h = h; return x.u; }
__device__ inline uint duph(float f) {
  union { _Float16 h; ushort u; } x; x.h = (_Float16)f;
  return ((uint)x.u << 16) | x.u;
}

// ---------------------------------------------------------------------------
// K0: folded bias + bf16-split offset-conv weight frags. 36 blocks.
// ---------------------------------------------------------------------------
__global__ __launch_bounds__(256) void prep0_k(
    const float* __restrict__ wof, const float* __restrict__ bias,
    const float* __restrict__ gamma, const float* __restrict__ beta,
    const float* __restrict__ mean, const float* __restrict__ var,
    float* __restrict__ ws) {
  const int tid = blockIdx.x * 256 + threadIdx.x;   // < 9216
  if (tid < 256) {
    const float iv = gamma[tid] * rsqrtf(var[tid] + 1e-5f);
    ws[BF2 + tid] = bias[tid] * iv + beta[tid] - mean[tid] * iv;
  }
  {
    const int l2  = tid & 63;
    const int mt  = (tid >> 6) & 1;
    const int i2  = tid >> 7;
    const int cg2 = i2 / 9;
    const int kk2 = i2 - cg2 * 9;
    const int oc  = (mt << 4) + (l2 & 15);
    const int cb2 = (cg2 << 5) + ((l2 >> 4) << 3);
    b8 ph, pl;
#pragma unroll
    for (int j = 0; j < 8; ++j) {
      const float v = (oc < 18) ? wof[((oc << 8) + cb2 + j) * 9 + kk2] : 0.f;
      const ushort h = f2bf(v);
      const float hf = __uint_as_float((uint)h << 16);
      ph[j] = (short)h;
      pl[j] = (short)f2bf(v - hf);
    }
    *(b8*)((short*)(ws + WH2) + tid * 8) = ph;
    *(b8*)((short*)(ws + WL2) + tid * 8) = pl;
  }
}

// ---------------------------------------------------------------------------
// K1: fused pack + transpose + offset-conv. Grid 2848:
//   bid < 288  : A-frag pack block (moved OFF the tail — R19).
//   else u = bid-288 (0..2559): r = u%5;
//     r < 4  -> transpose block 4*(u/5)+r   (2048 blocks)
//     r == 4 -> offset block g = u/5        (512 blocks)
// Offset blocks now own 2 cg-pairs each (4 staging iterations, K=1152
// half): staging/conversion duplication x2 instead of x4, while keeping
// >=2 co-resident offset blocks per CU (R17 lesson: 1/CU serializes).
// Partials plain-stored to 2 private slices; K2 folds them.
// ---------------------------------------------------------------------------
__global__ __launch_bounds__(256, 4) void mid_k(
    const float* __restrict__ x, const float* __restrict__ w,
    const float* __restrict__ gamma, const float* __restrict__ var,
    float* __restrict__ ws) {
  __shared__ __align__(16) ushort Xh[3][66][40];
  __shared__ __align__(16) ushort Xl[3][66][40];
  const int bid = blockIdx.x;
  const int t   = threadIdx.x;

  if (bid < 288) {
    // ---- main-GEMM A-frag pack ----
    const int tid = bid * 256 + t;            // < 73728
    const int l  = tid & 63;
    const int ot = (tid >> 6) & 15;
    const int f  = tid >> 10;
    const int o  = (ot << 4) + (l & 15);
    const float inv = gamma[o] * rsqrtf(var[o] + 1e-5f);
    const int s  = f & 1;
    const int g  = f >> 1;
    const int cw = g / 9;
    const int kk = g - cw * 9;
    const int cb = (cw << 6) + (s << 5) + ((l >> 4) << 3);
    h8 pk;
#pragma unroll
    for (int j = 0; j < 8; ++j)
      pk[j] = (_Float16)(w[((o << 8) + cb + j) * 9 + kk] * inv);
    *(h8*)((_Float16*)(ws + AF2) + tid * 8) = pk;
    return;
  }

  const int u = bid - 288;
  const int r = u % 5;
  const int g5 = u / 5;
  if (r != 4) {
    // ---- transpose: x (B,C,H,W) fp32 -> xt (B,P,C) f16 ----
    const int id  = ((g5 << 2) + r) * 256 + t;   // < 524288
    const int p   = id & 4095;
    const int cg8 = (id >> 12) & 31;
    const int b   = id >> 17;
    const float* xp = x + (((long)(b * 256 + cg8 * 8)) << 12) + p;
    _Float16* xt = (_Float16*)(ws + XT2);
    h8 pk;
#pragma unroll
    for (int j = 0; j < 8; ++j) pk[j] = (_Float16)xp[(long)j << 12];
    *(h8*)(xt + ((((long)(b << 12) + p)) << 8) + (cg8 << 3)) = pk;
    return;
  }

  // ---- offset conv block g5 in [0,512): (q,b,ho), cg = 4q..4q+3 ----
  const int g   = g5;
  const int q   = g >> 8;                     // 0..1
  const int b   = (g >> 6) & 3;
  const int ho  = g & 63;
  const int l   = t & 63;
  const int wv  = t >> 6;
  const short* afh = (const short*)(ws + WH2);
  const short* afl = (const short*)(ws + WL2);

  for (int uu = t; uu < 240; uu += 256) {
    const int row = uu / 80, rem = uu % 80;
    const int col = (rem >= 40) ? 65 : 0;
    const int c   = rem % 40;
    Xh[row][col][c] = 0;
    Xl[row][col][c] = 0;
  }

  f4 acc[2];
  acc[0] = f4{0.f, 0.f, 0.f, 0.f};
  acc[1] = f4{0.f, 0.f, 0.f, 0.f};

  const int cidx = t >> 3;
  const int j8   = t & 7;
  const float* xc = x + ((long)b << 20) + ((long)cidx << 12);
  const int col = (wv << 4) + (l & 15);
  const int qc  = (l >> 4) << 3;

  for (int it = 0; it < 4; ++it) {
    const int cg = (q << 2) + it;
    __syncthreads();
    const float* xg = xc + ((long)(cg << 5) << 12);
#pragma unroll
    for (int rep = 0; rep < 6; ++rep) {
      const int fi   = (rep << 3) + j8;
      const int row  = fi >> 4;
      const int colf = (fi & 15) << 2;
      const int y = ho - 1 + row;
      f4u v = {0.f, 0.f, 0.f, 0.f};
      if (y >= 0 && y <= 63) v = *(const f4u*)(xg + (y << 6) + colf);
#pragma unroll
      for (int qq = 0; qq < 4; ++qq) {
        const ushort h = f2bf(v[qq]);
        const float hf = __uint_as_float((uint)h << 16);
        Xh[row][colf + 1 + qq][cidx] = h;
        Xl[row][colf + 1 + qq][cidx] = f2bf(v[qq] - hf);
      }
    }
    __syncthreads();
#pragma unroll
    for (int kk = 0; kk < 9; ++kk) {
      const int ky = kk / 3, kx = kk - ky * 3;
      const int i  = cg * 9 + kk;
      const b8 ah0 = *(const b8*)(afh + ((((i << 1) + 0) << 6) + l) * 8);
      const b8 ah1 = *(const b8*)(afh + ((((i << 1) + 1) << 6) + l) * 8);
      const b8 al0 = *(const b8*)(afl + ((((i << 1) + 0) << 6) + l) * 8);
      const b8 al1 = *(const b8*)(afl + ((((i << 1) + 1) << 6) + l) * 8);
      const b8 bh = *(const b8*)&Xh[ky][col + kx][qc];
      const b8 bl = *(const b8*)&Xl[ky][col + kx][qc];
      acc[0] = __builtin_amdgcn_mfma_f32_16x16x32_bf16(ah0, bh, acc[0], 0, 0, 0);
      acc[0] = __builtin_amdgcn_mfma_f32_16x16x32_bf16(ah0, bl, acc[0], 0, 0, 0);
      acc[0] = __builtin_amdgcn_mfma_f32_16x16x32_bf16(al0, bh, acc[0], 0, 0, 0);
      acc[1] = __builtin_amdgcn_mfma_f32_16x16x32_bf16(ah1, bh, acc[1], 0, 0, 0);
      acc[1] = __builtin_amdgcn_mfma_f32_16x16x32_bf16(ah1, bl, acc[1], 0, 0, 0);
      acc[1] = __builtin_amdgcn_mfma_f32_16x16x32_bf16(al1, bh, acc[1], 0, 0, 0);
    }
  }

  // plain stores into the q-private partial slice (full coverage, no zeroing)
  float* ofs = ws + (q == 0 ? OF2 : OFPG);
  const int wo = col;
  const int q4 = (l >> 4) << 2;
#pragma unroll
  for (int mt = 0; mt < 2; ++mt)
#pragma unroll
    for (int rr = 0; rr < 4; ++rr) {
      const int oc = (mt << 4) + q4 + rr;
      if (oc < 18)
        ofs[((b * 18 + oc) << 12) + (ho << 6) + wo] = acc[mt][rr];
    }
}

// ---------------------------------------------------------------------------
// K2: f16 MFMA GEMM with fused descriptor computation (R16 structure).
// 256 blocks x 512 threads, 64-sample tiles. Descriptor phase folds the
// 2 q-partial slices (4 scalar L2 reads per descriptor, once per block).
// ---------------------------------------------------------------------------
__global__ __launch_bounds__(512, 2) void deform_gemm_f16b(
    const float* __restrict__ ws, const float* __restrict__ bof,
    float* __restrict__ out) {
  __shared__ __align__(16) uint Bs[3][64][32];   // 24 KB f16 tiles
  __shared__ uint4 dW[576];                      // 9 KB
  __shared__ int4  dP[576];                      // 9 KB

  const int t     = threadIdx.x;
  const int bid   = blockIdx.x;
  const int xcd   = bid & 7;
  const int batch = xcd >> 1;
  const int half  = xcd & 1;
  const int j     = bid >> 3;                    // 0..31
  const int sp0   = (half << 11) + (j << 6);
  const int l     = t & 63;
  const int wv    = t >> 6;                      // 0..7

  const int sn  = ((wv & 3) << 4) | (l & 15);    // sample column 0..63
  const int cg8 = ((wv >> 2) << 2) | (l >> 4);   // 8-ch slice 0..7
  const uint* xtu = (const uint*)(ws + XT2) + ((long)batch << 19);
  const _Float16* af = (const _Float16*)(ws + AF2);

  // ---- fused descriptor computation: 576 = 9 kk x 64 samples ----
  const float* of0 = ws + OF2;
  const float* of1 = ws + OFPG;
  for (int u = t; u < 576; u += 512) {
    const int kk = u >> 6, s = u & 63;
    const int sp = sp0 + s;
    const int ho = sp >> 6, wo = sp & 63;
    const int ky = kk / 3, kx = kk - ky * 3;
    const int oy = ((batch * 18 + (kk << 1)) << 12) + sp;
    const int ox = oy + 4096;
    const float dy = of0[oy] + of1[oy] + bof[kk << 1];
    const float dx = of0[ox] + of1[ox] + bof[(kk << 1) + 1];
    const float py = (float)(ho - 1 + ky) + dy;
    const float px = (float)(wo - 1 + kx) + dx;
    const float y0f = floorf(py), x0f = floorf(px);
    const float ly = py - y0f, lx = px - x0f;
    const int y0 = (int)y0f, x0 = (int)x0f;
    const int y1 = y0 + 1, x1 = x0 + 1;
    const float vy0 = (y0 >= 0 && y0 < 64) ? 1.f : 0.f;
    const float vy1 = (y1 >= 0 && y1 < 64) ? 1.f : 0.f;
    const float vx0 = (x0 >= 0 && x0 < 64) ? 1.f : 0.f;
    const float vx1 = (x1 >= 0 && x1 < 64) ? 1.f : 0.f;
    const int y0c = min(max(y0, 0), 63), y1c = min(max(y1, 0), 63);
    const int x0c = min(max(x0, 0), 63), x1c = min(max(x1, 0), 63);
    uint4 wv4;
    wv4.x = duph((1.f - ly) * (1.f - lx) * vy0 * vx0);
    wv4.y = duph((1.f - ly) * lx * vy0 * vx1);
    wv4.z = duph(ly * (1.f - lx) * vy1 * vx0);
    wv4.w = duph(ly * lx * vy1 * vx1);
    int4 pv;
    pv.x = (y0c << 6) + x0c;
    pv.y = (y0c << 6) + x1c;
    pv.z = (y1c << 6) + x0c;
    pv.w = (y1c << 6) + x1c;
    dW[u] = wv4;
    dP[u] = pv;
  }
  __syncthreads();

  f4 acc[2][4];
#pragma unroll
  for (int m = 0; m < 2; ++m)
#pragma unroll
    for (int nt = 0; nt < 4; ++nt) acc[m][nt] = f4{0.f, 0.f, 0.f, 0.f};

  uint4 cset0[4], cset1[4];
  uint4 w0v, w1v, wq; int4 pq;
  h8 aA[2][2], aN[2][2];
  int kkd, kkg, cwg, bufc;

#define FRDD(W_, P_, KK_) do { const int u_ = ((KK_) << 6) + sn;             \
    W_ = dW[u_]; P_ = dP[u_]; } while (0)

#define FGATH(DST_, P_) do {                                                 \
    const int co_ = (cwg << 5) + (cg8 << 2);                                 \
    DST_[0] = *(const uint4*)(xtu + ((P_).x << 7) + co_);                    \
    DST_[1] = *(const uint4*)(xtu + ((P_).y << 7) + co_);                    \
    DST_[2] = *(const uint4*)(xtu + ((P_).z << 7) + co_);                    \
    DST_[3] = *(const uint4*)(xtu + ((P_).w << 7) + co_);                    \
  } while (0)

#define FCOMB(CS_, WV_, BUF_) do {                                           \
    const h2 wc0_ = u2h2((WV_).x), wc1_ = u2h2((WV_).y);                     \
    const h2 wc2_ = u2h2((WV_).z), wc3_ = u2h2((WV_).w);                     \
    uint4 r_;                                                                \
    r_.x = h22u(u2h2(CS_[0].x) * wc0_ + u2h2(CS_[1].x) * wc1_ +              \
                u2h2(CS_[2].x) * wc2_ + u2h2(CS_[3].x) * wc3_);              \
    r_.y = h22u(u2h2(CS_[0].y) * wc0_ + u2h2(CS_[1].y) * wc1_ +              \
                u2h2(CS_[2].y) * wc2_ + u2h2(CS_[3].y) * wc3_);              \
    r_.z = h22u(u2h2(CS_[0].z) * wc0_ + u2h2(CS_[1].z) * wc1_ +              \
                u2h2(CS_[2].z) * wc2_ + u2h2(CS_[3].z) * wc3_);              \
    r_.w = h22u(u2h2(CS_[0].w) * wc0_ + u2h2(CS_[1].w) * wc1_ +              \
                u2h2(CS_[2].w) * wc2_ + u2h2(CS_[3].w) * wc3_);              \
    *(uint4*)&Bs[BUF_][sn][(cg8 ^ (sn & 7)) << 2] = r_;                      \
  } while (0)

#define FLOADA(I_, DST_) do {                                                \
    _Pragma("unroll")                                                        \
    for (int m = 0; m < 2; ++m)                                              \
      _Pragma("unroll")                                                      \
      for (int s = 0; s < 2; ++s) {                                          \
        const int f_ = ((I_) << 1) + s;                                      \
        DST_[m][s] = *(const h8*)(af +                                       \
            ((((f_ << 4) + (wv << 1) + m) << 6) + l) * 8);                   \
      }                                                                      \
  } while (0)

#define FMFMA(AC_, BUF_) do {                                                \
    h8 bB_[4][2];                                                            \
    _Pragma("unroll")                                                        \
    for (int nt = 0; nt < 4; ++nt)                                           \
      _Pragma("unroll")                                                      \
      for (int s = 0; s < 2; ++s) {                                          \
        const int snr_ = (nt << 4) + (l & 15);                               \
        const int ph_  = (((s << 2) + (l >> 4)) ^ (snr_ & 7)) << 2;          \
        bB_[nt][s] = *(const h8*)&Bs[BUF_][snr_][ph_];                       \
      }                                                                      \
    _Pragma("unroll")                                                        \
    for (int m = 0; m < 2; ++m)                                              \
      _Pragma("unroll")                                                      \
      for (int nt = 0; nt < 4; ++nt) {                                       \
        acc[m][nt] = __builtin_amdgcn_mfma_f32_16x16x32_f16(                 \
            AC_[m][0], bB_[nt][0], acc[m][nt], 0, 0, 0);                     \
        acc[m][nt] = __builtin_amdgcn_mfma_f32_16x16x32_f16(                 \
            AC_[m][1], bB_[nt][1], acc[m][nt], 0, 0, 0);                     \
      }                                                                      \
  } while (0)

#define FBODY(I_, AC_, AN_, CC_, WC_, CN_, WN_) do {                         \
    if ((I_) < 34) {                                                         \
      WN_ = wq; FGATH(CN_, pq);                                              \
      kkg++; if (kkg == 9) { kkg = 0; cwg++; }                               \
    }                                                                        \
    if ((I_) < 33) { FRDD(wq, pq, kkd); kkd = (kkd == 8) ? 0 : kkd + 1; }    \
    const int bufn_ = (bufc == 2) ? 0 : bufc + 1;                            \
    FMFMA(AC_, bufc);                                                        \
    if ((I_) < 35) {                                                         \
      FLOADA((I_) + 1, AN_);                                                 \
      FCOMB(CC_, WC_, bufn_);                                                \
    }                                                                        \
    bufc = bufn_;                                                            \
    BARRIER_RELAX();                                                         \
  } while (0)

  {
    uint4 wA; int4 pA;
    cwg = 0;
    FRDD(wA, pA, 0);
    FGATH(cset0, pA);
    FRDD(w1v, pA, 1);
    FGATH(cset1, pA);
    FRDD(wq, pq, 2);
    FLOADA(0, aA);
    FCOMB(cset0, wA, 0);
    kkd = 3; kkg = 2; bufc = 0;
  }
  BARRIER_RELAX();

  for (int i = 0; i < 36; i += 2) {
    FBODY(i,     aA, aN, cset1, w1v, cset0, w0v);
    FBODY(i + 1, aN, aA, cset0, w0v, cset1, w1v);
  }

  const float* bfold = ws + BF2;
  const int quad = l >> 4;
#pragma unroll
  for (int m = 0; m < 2; ++m) {
    const int ob = (((wv << 1) + m) << 4) + (quad << 2);
    const f4 bf = *(const f4*)&bfold[ob];
#pragma unroll
    for (int nt = 0; nt < 4; ++nt) {
      const int sp = sp0 + (nt << 4) + (l & 15);
#pragma unroll
      for (int rr = 0; rr < 4; ++rr) {
        out[(((batch << 8) + ob + rr) << 12) + sp] =
            fmaxf(acc[m][nt][rr] + bf[rr], 0.f);
      }
    }
  }
}

// ---------------------------------------------------------------------------
extern "C" void kernel_launch(void* const* d_in, const int* in_sizes, int n_in,
                              void* d_out, int out_size, void* d_ws, size_t ws_size,
                              hipStream_t stream) {
  const float* x     = (const float*)d_in[0];
  const float* wof   = (const float*)d_in[1];
  const float* bof   = (const float*)d_in[2];
  const float* w     = (const float*)d_in[3];
  const float* bias  = (const float*)d_in[4];
  const float* gamma = (const float*)d_in[5];
  const float* beta  = (const float*)d_in[6];
  const float* mean  = (const float*)d_in[7];
  const float* var   = (const float*)d_in[8];
  float* out = (float*)d_out;
  float* ws  = (float*)d_ws;

  hipLaunchKernelGGL(prep0_k, dim3(36), dim3(256), 0, stream,
                     wof, bias, gamma, beta, mean, var, ws);
  hipLaunchKernelGGL(mid_k, dim3(2848), dim3(256), 0, stream,
                     x, w, gamma, var, ws);
  hipLaunchKernelGGL(deform_gemm_f16b, dim3(256), dim3(512), 0, stream,
                     ws, bof, out);
}

// Round 7
// 149.462 us; speedup vs baseline: 1.1003x; 1.1003x over previous
//
#include <hip/hip_runtime.h>
#include <math.h>

typedef __attribute__((ext_vector_type(8))) short b8;
typedef __attribute__((ext_vector_type(4))) float f4;
typedef float f4u __attribute__((ext_vector_type(4), aligned(4)));
typedef _Float16 h8 __attribute__((ext_vector_type(8)));
typedef _Float16 h2 __attribute__((ext_vector_type(2)));

// ---------------- ws layout (float offsets) --------------------------------
#define XT2   0                     // f16[4*4096*256] = 2097152 floats
#define OF2   2097152               // 294912 (fp32 accumulated offsets)
#define WH2   2392064               // bf16-split offset-conv weights (hi)
#define WL2   2428928               // (lo)
#define AF2   3571712               // f16[589824] main A-frags
#define BF2   3866624               // 256 folded bias

// Raw barrier: drain LDS only, leave register-destined global loads in
// flight across the barrier.
#define BARRIER_RELAX() do {                                   \
    asm volatile("s_waitcnt lgkmcnt(0)" ::: "memory");         \
    __builtin_amdgcn_s_barrier();                              \
  } while (0)

__device__ inline ushort f2bf(float f) {
  uint u = __float_as_uint(f);
  return (ushort)((u + 0x7FFFu + ((u >> 16) & 1u)) >> 16);
}
__device__ inline h2 u2h2(uint u) { union { uint u; h2 h; } x; x.u = u; return x.h; }
__device__ inline uint h22u(h2 h) { union { uint u; h2 h; } x; x.h = h; return x.u; }
__device__ inline uint duph(float f) {
  union { _Float16 h; ushort u; } x; x.h = (_Float16)f;
  return ((uint)x.u << 16) | x.u;
}

// ---------------------------------------------------------------------------
// K0 (R16 verbatim): zero OF2, folded bias, bf16-split offset weights.
// ---------------------------------------------------------------------------
__global__ __launch_bounds__(256) void prep0_k(
    const float* __restrict__ wof, const float* __restrict__ bias,
    const float* __restrict__ gamma, const float* __restrict__ beta,
    const float* __restrict__ mean, const float* __restrict__ var,
    float* __restrict__ ws) {
  const int tid = blockIdx.x * 256 + threadIdx.x;   // < 73728
  ((f4*)(ws + OF2))[tid] = f4{0.f, 0.f, 0.f, 0.f};
  if (tid < 256) {
    const float iv = gamma[tid] * rsqrtf(var[tid] + 1e-5f);
    ws[BF2 + tid] = bias[tid] * iv + beta[tid] - mean[tid] * iv;
  }
  if (tid < 9216) {
    const int l2  = tid & 63;
    const int mt  = (tid >> 6) & 1;
    const int i2  = tid >> 7;
    const int cg2 = i2 / 9;
    const int kk2 = i2 - cg2 * 9;
    const int oc  = (mt << 4) + (l2 & 15);
    const int cb2 = (cg2 << 5) + ((l2 >> 4) << 3);
    b8 ph, pl;
#pragma unroll
    for (int j = 0; j < 8; ++j) {
      const float v = (oc < 18) ? wof[((oc << 8) + cb2 + j) * 9 + kk2] : 0.f;
      const ushort h = f2bf(v);
      const float hf = __uint_as_float((uint)h << 16);
      ph[j] = (short)h;
      pl[j] = (short)f2bf(v - hf);
    }
    *(b8*)((short*)(ws + WH2) + tid * 8) = ph;
    *(b8*)((short*)(ws + WL2) + tid * 8) = pl;
  }
}

// ---------------------------------------------------------------------------
// K1 (R16 verbatim): fused transpose + offset-conv + A-frag pack. Grid 3360.
// ---------------------------------------------------------------------------
__global__ __launch_bounds__(256, 4) void mid_k(
    const float* __restrict__ x, const float* __restrict__ w,
    const float* __restrict__ gamma, const float* __restrict__ var,
    float* __restrict__ ws) {
  __shared__ __align__(16) ushort Xh[3][66][40];
  __shared__ __align__(16) ushort Xl[3][66][40];
  const int bid = blockIdx.x;
  const int t   = threadIdx.x;

  if (bid >= 3072) {
    // ---- main-GEMM A-frag pack ----
    const int tid = (bid - 3072) * 256 + t;   // < 73728
    const int l  = tid & 63;
    const int ot = (tid >> 6) & 15;
    const int f  = tid >> 10;
    const int o  = (ot << 4) + (l & 15);
    const float inv = gamma[o] * rsqrtf(var[o] + 1e-5f);
    const int s  = f & 1;
    const int g  = f >> 1;
    const int cw = g / 9;
    const int kk = g - cw * 9;
    const int cb = (cw << 6) + (s << 5) + ((l >> 4) << 3);
    h8 pk;
#pragma unroll
    for (int j = 0; j < 8; ++j)
      pk[j] = (_Float16)(w[((o << 8) + cb + j) * 9 + kk] * inv);
    *(h8*)((_Float16*)(ws + AF2) + tid * 8) = pk;
    return;
  }

  const int r = bid % 3;
  const int g = bid / 3;
  if (r != 2) {
    // ---- transpose: x (B,C,H,W) fp32 -> xt (B,P,C) f16 ----
    const int id  = ((g << 1) + r) * 256 + t;   // < 524288
    const int p   = id & 4095;
    const int cg8 = (id >> 12) & 31;
    const int b   = id >> 17;
    const float* xp = x + (((long)(b * 256 + cg8 * 8)) << 12) + p;
    _Float16* xt = (_Float16*)(ws + XT2);
    h8 pk;
#pragma unroll
    for (int j = 0; j < 8; ++j) pk[j] = (_Float16)xp[(long)j << 12];
    *(h8*)(xt + ((((long)(b << 12) + p)) << 8) + (cg8 << 3)) = pk;
    return;
  }

  // ---- offset conv block g ----
  const int q   = g >> 8;
  const int b   = (g >> 6) & 3;
  const int ho  = g & 63;
  const int l   = t & 63;
  const int wv  = t >> 6;
  const short* afh = (const short*)(ws + WH2);
  const short* afl = (const short*)(ws + WL2);

  for (int u = t; u < 240; u += 256) {
    const int row = u / 80, rem = u % 80;
    const int col = (rem >= 40) ? 65 : 0;
    const int c   = rem % 40;
    Xh[row][col][c] = 0;
    Xl[row][col][c] = 0;
  }

  f4 acc[2];
  acc[0] = f4{0.f, 0.f, 0.f, 0.f};
  acc[1] = f4{0.f, 0.f, 0.f, 0.f};

  const int cidx = t >> 3;
  const int j8   = t & 7;
  const float* xc = x + ((long)b << 20) + ((long)cidx << 12);
  const int col = (wv << 4) + (l & 15);
  const int qc  = (l >> 4) << 3;

  for (int it = 0; it < 2; ++it) {
    const int cg = (q << 1) + it;
    __syncthreads();
    const float* xg = xc + ((long)(cg << 5) << 12);
#pragma unroll
    for (int rep = 0; rep < 6; ++rep) {
      const int fi   = (rep << 3) + j8;
      const int row  = fi >> 4;
      const int colf = (fi & 15) << 2;
      const int y = ho - 1 + row;
      f4u v = {0.f, 0.f, 0.f, 0.f};
      if (y >= 0 && y <= 63) v = *(const f4u*)(xg + (y << 6) + colf);
#pragma unroll
      for (int qq = 0; qq < 4; ++qq) {
        const ushort h = f2bf(v[qq]);
        const float hf = __uint_as_float((uint)h << 16);
        Xh[row][colf + 1 + qq][cidx] = h;
        Xl[row][colf + 1 + qq][cidx] = f2bf(v[qq] - hf);
      }
    }
    __syncthreads();
#pragma unroll
    for (int kk = 0; kk < 9; ++kk) {
      const int ky = kk / 3, kx = kk - ky * 3;
      const int i  = cg * 9 + kk;
      const b8 ah0 = *(const b8*)(afh + ((((i << 1) + 0) << 6) + l) * 8);
      const b8 ah1 = *(const b8*)(afh + ((((i << 1) + 1) << 6) + l) * 8);
      const b8 al0 = *(const b8*)(afl + ((((i << 1) + 0) << 6) + l) * 8);
      const b8 al1 = *(const b8*)(afl + ((((i << 1) + 1) << 6) + l) * 8);
      const b8 bh = *(const b8*)&Xh[ky][col + kx][qc];
      const b8 bl = *(const b8*)&Xl[ky][col + kx][qc];
      acc[0] = __builtin_amdgcn_mfma_f32_16x16x32_bf16(ah0, bh, acc[0], 0, 0, 0);
      acc[0] = __builtin_amdgcn_mfma_f32_16x16x32_bf16(ah0, bl, acc[0], 0, 0, 0);
      acc[0] = __builtin_amdgcn_mfma_f32_16x16x32_bf16(al0, bh, acc[0], 0, 0, 0);
      acc[1] = __builtin_amdgcn_mfma_f32_16x16x32_bf16(ah1, bh, acc[1], 0, 0, 0);
      acc[1] = __builtin_amdgcn_mfma_f32_16x16x32_bf16(ah1, bl, acc[1], 0, 0, 0);
      acc[1] = __builtin_amdgcn_mfma_f32_16x16x32_bf16(al1, bh, acc[1], 0, 0, 0);
    }
  }

  const int wo = col;
  const int q4 = (l >> 4) << 2;
#pragma unroll
  for (int mt = 0; mt < 2; ++mt)
#pragma unroll
    for (int rr = 0; rr < 4; ++rr) {
      const int oc = (mt << 4) + q4 + rr;
      if (oc < 18)
        atomicAdd(&ws[OF2 + ((b * 18 + oc) << 12) + (ho << 6) + wo],
                  acc[mt][rr]);
    }
}

// ---------------------------------------------------------------------------
// K2 (R20): 256 blocks x 512 threads, 64-sample tiles. Restructured loop:
//   - Bs 4 buffers; COMB writes step j+2 (write->read always crosses a
//     barrier); ONE barrier per 2 kk-steps (18 instead of 36).
//   - Gather pipeline deepened: FGATH at iter j fetches step j+3, combined
//     at iter j+2 (2-iteration latency absorption vs 1).
//   - s_setprio(1) around the MFMA cluster (T5).
// ---------------------------------------------------------------------------
__global__ __launch_bounds__(512, 2) void deform_gemm_f16b(
    const float* __restrict__ ws, const float* __restrict__ bof,
    float* __restrict__ out) {
  __shared__ __align__(16) uint Bs[4][64][32];   // 32 KB f16 tiles
  __shared__ uint4 dW[576];                      // 9 KB
  __shared__ int4  dP[576];                      // 9 KB

  const int t     = threadIdx.x;
  const int bid   = blockIdx.x;
  const int xcd   = bid & 7;
  const int batch = xcd >> 1;
  const int half  = xcd & 1;
  const int j     = bid >> 3;                    // 0..31
  const int sp0   = (half << 11) + (j << 6);
  const int l     = t & 63;
  const int wv    = t >> 6;                      // 0..7

  const int sn  = ((wv & 3) << 4) | (l & 15);    // sample column 0..63
  const int cg8 = ((wv >> 2) << 2) | (l >> 4);   // 8-ch slice 0..7
  const uint* xtu = (const uint*)(ws + XT2) + ((long)batch << 19);
  const _Float16* af = (const _Float16*)(ws + AF2);

  // ---- fused descriptor computation: 576 = 9 kk x 64 samples ----
  for (int u = t; u < 576; u += 512) {
    const int kk = u >> 6, s = u & 63;
    const int sp = sp0 + s;
    const int ho = sp >> 6, wo = sp & 63;
    const int ky = kk / 3, kx = kk - ky * 3;
    const float dy =
        ws[OF2 + ((batch * 18 + (kk << 1)) << 12) + sp] + bof[kk << 1];
    const float dx =
        ws[OF2 + ((batch * 18 + (kk << 1) + 1) << 12) + sp] + bof[(kk << 1) + 1];
    const float py = (float)(ho - 1 + ky) + dy;
    const float px = (float)(wo - 1 + kx) + dx;
    const float y0f = floorf(py), x0f = floorf(px);
    const float ly = py - y0f, lx = px - x0f;
    const int y0 = (int)y0f, x0 = (int)x0f;
    const int y1 = y0 + 1, x1 = x0 + 1;
    const float vy0 = (y0 >= 0 && y0 < 64) ? 1.f : 0.f;
    const float vy1 = (y1 >= 0 && y1 < 64) ? 1.f : 0.f;
    const float vx0 = (x0 >= 0 && x0 < 64) ? 1.f : 0.f;
    const float vx1 = (x1 >= 0 && x1 < 64) ? 1.f : 0.f;
    const int y0c = min(max(y0, 0), 63), y1c = min(max(y1, 0), 63);
    const int x0c = min(max(x0, 0), 63), x1c = min(max(x1, 0), 63);
    uint4 wv4;
    wv4.x = duph((1.f - ly) * (1.f - lx) * vy0 * vx0);
    wv4.y = duph((1.f - ly) * lx * vy0 * vx1);
    wv4.z = duph(ly * (1.f - lx) * vy1 * vx0);
    wv4.w = duph(ly * lx * vy1 * vx1);
    int4 pv;
    pv.x = (y0c << 6) + x0c;
    pv.y = (y0c << 6) + x1c;
    pv.z = (y1c << 6) + x0c;
    pv.w = (y1c << 6) + x1c;
    dW[u] = wv4;
    dP[u] = pv;
  }
  __syncthreads();

  f4 acc[2][4];
#pragma unroll
  for (int m = 0; m < 2; ++m)
#pragma unroll
    for (int nt = 0; nt < 4; ++nt) acc[m][nt] = f4{0.f, 0.f, 0.f, 0.f};

  uint4 cset0[4], cset1[4];
  uint4 w0v, w1v, wq; int4 pq;
  h8 aA[2][2], aN[2][2];
  int kkd, kkg, cwg;

#define FRDD(W_, P_, KK_) do { const int u_ = ((KK_) << 6) + sn;             \
    W_ = dW[u_]; P_ = dP[u_]; } while (0)

#define FGATH(DST_, P_) do {                                                 \
    const int co_ = (cwg << 5) + (cg8 << 2);                                 \
    DST_[0] = *(const uint4*)(xtu + ((P_).x << 7) + co_);                    \
    DST_[1] = *(const uint4*)(xtu + ((P_).y << 7) + co_);                    \
    DST_[2] = *(const uint4*)(xtu + ((P_).z << 7) + co_);                    \
    DST_[3] = *(const uint4*)(xtu + ((P_).w << 7) + co_);                    \
  } while (0)

#define FCOMB(CS_, WV_, BUF_) do {                                           \
    const h2 wc0_ = u2h2((WV_).x), wc1_ = u2h2((WV_).y);                     \
    const h2 wc2_ = u2h2((WV_).z), wc3_ = u2h2((WV_).w);                     \
    uint4 r_;                                                                \
    r_.x = h22u(u2h2(CS_[0].x) * wc0_ + u2h2(CS_[1].x) * wc1_ +              \
                u2h2(CS_[2].x) * wc2_ + u2h2(CS_[3].x) * wc3_);              \
    r_.y = h22u(u2h2(CS_[0].y) * wc0_ + u2h2(CS_[1].y) * wc1_ +              \
                u2h2(CS_[2].y) * wc2_ + u2h2(CS_[3].y) * wc3_);              \
    r_.z = h22u(u2h2(CS_[0].z) * wc0_ + u2h2(CS_[1].z) * wc1_ +              \
                u2h2(CS_[2].z) * wc2_ + u2h2(CS_[3].z) * wc3_);              \
    r_.w = h22u(u2h2(CS_[0].w) * wc0_ + u2h2(CS_[1].w) * wc1_ +              \
                u2h2(CS_[2].w) * wc2_ + u2h2(CS_[3].w) * wc3_);              \
    *(uint4*)&Bs[BUF_][sn][(cg8 ^ (sn & 7)) << 2] = r_;                      \
  } while (0)

#define FLOADA(I_, DST_) do {                                                \
    _Pragma("unroll")                                                        \
    for (int m = 0; m < 2; ++m)                                              \
      _Pragma("unroll")                                                      \
      for (int s = 0; s < 2; ++s) {                                          \
        const int f_ = ((I_) << 1) + s;                                      \
        DST_[m][s] = *(const h8*)(af +                                       \
            ((((f_ << 4) + (wv << 1) + m) << 6) + l) * 8);                   \
      }                                                                      \
  } while (0)

#define FMFMA(AC_, BUF_) do {                                                \
    h8 bB_[4][2];                                                            \
    _Pragma("unroll")                                                        \
    for (int nt = 0; nt < 4; ++nt)                                           \
      _Pragma("unroll")                                                      \
      for (int s = 0; s < 2; ++s) {                                          \
        const int snr_ = (nt << 4) + (l & 15);                               \
        const int ph_  = (((s << 2) + (l >> 4)) ^ (snr_ & 7)) << 2;          \
        bB_[nt][s] = *(const h8*)&Bs[BUF_][snr_][ph_];                       \
      }                                                                      \
    _Pragma("unroll")                                                        \
    for (int m = 0; m < 2; ++m)                                              \
      _Pragma("unroll")                                                      \
      for (int nt = 0; nt < 4; ++nt) {                                       \
        acc[m][nt] = __builtin_amdgcn_mfma_f32_16x16x32_f16(                 \
            AC_[m][0], bB_[nt][0], acc[m][nt], 0, 0, 0);                     \
        acc[m][nt] = __builtin_amdgcn_mfma_f32_16x16x32_f16(                 \
            AC_[m][1], bB_[nt][1], acc[m][nt], 0, 0, 0);                     \
      }                                                                      \
  } while (0)

// One macro = 2 kk-steps (even je_, odd jo_), single barrier at the end.
// Pipeline distances: FGATH(j) = step j+3 (combined at j+2, MFMA'd at j+2's
// read); FRDD(j) = step j+4; FCOMB(j) writes buf (j+2)&3; FMFMA(j) reads
// buf j&3. Write->read of every Bs buffer crosses the barrier after the
// odd step of its pair.
#define FBODY2(J_) do {                                                      \
    const int je_ = (J_);                                                    \
    if (je_ < 33) { w0v = wq; FGATH(cset0, pq);                              \
      kkg++; if (kkg == 9) { kkg = 0; cwg++; } }                             \
    if (je_ < 32) { FRDD(wq, pq, kkd); kkd = (kkd == 8) ? 0 : kkd + 1; }     \
    __builtin_amdgcn_s_setprio(1);                                           \
    FMFMA(aA, (je_ & 3));                                                    \
    __builtin_amdgcn_s_setprio(0);                                           \
    if (je_ < 35) FLOADA(je_ + 1, aN);                                       \
    if (je_ < 34) FCOMB(cset1, w1v, ((je_ + 2) & 3));                        \
    const int jo_ = (J_) + 1;                                                \
    if (jo_ < 33) { w1v = wq; FGATH(cset1, pq);                              \
      kkg++; if (kkg == 9) { kkg = 0; cwg++; } }                             \
    if (jo_ < 32) { FRDD(wq, pq, kkd); kkd = (kkd == 8) ? 0 : kkd + 1; }     \
    __builtin_amdgcn_s_setprio(1);                                           \
    FMFMA(aN, (jo_ & 3));                                                    \
    __builtin_amdgcn_s_setprio(0);                                           \
    if (jo_ < 35) FLOADA(jo_ + 1, aA);                                       \
    if (jo_ < 34) FCOMB(cset0, w0v, ((jo_ + 2) & 3));                        \
    BARRIER_RELAX();                                                         \
  } while (0)

  {
    uint4 wA, wB; int4 pA;
    cwg = 0;
    FRDD(wA, pA, 0); FGATH(cset0, pA);       // step 0
    FRDD(wB, pA, 1); FGATH(cset1, pA);       // step 1
    FCOMB(cset0, wA, 0);                     // buf0 = step 0
    FCOMB(cset1, wB, 1);                     // buf1 = step 1
    FRDD(w1v, pA, 2); FGATH(cset1, pA);      // step 2 -> cset1 (W1 = w(2))
    FRDD(wq, pq, 3);                         // step 3 descriptors
    FLOADA(0, aA);                           // A(0)
    kkd = 4; kkg = 3;                        // next FRDD kk / gather roll
  }
  BARRIER_RELAX();

  for (int i = 0; i < 36; i += 2) FBODY2(i);

  const float* bfold = ws + BF2;
  const int quad = l >> 4;
#pragma unroll
  for (int m = 0; m < 2; ++m) {
    const int ob = (((wv << 1) + m) << 4) + (quad << 2);
    const f4 bf = *(const f4*)&bfold[ob];
#pragma unroll
    for (int nt = 0; nt < 4; ++nt) {
      const int sp = sp0 + (nt << 4) + (l & 15);
#pragma unroll
      for (int rr = 0; rr < 4; ++rr) {
        out[(((batch << 8) + ob + rr) << 12) + sp] =
            fmaxf(acc[m][nt][rr] + bf[rr], 0.f);
      }
    }
  }
}

// ---------------------------------------------------------------------------
extern "C" void kernel_launch(void* const* d_in, const int* in_sizes, int n_in,
                              void* d_out, int out_size, void* d_ws, size_t ws_size,
                              hipStream_t stream) {
  const float* x     = (const float*)d_in[0];
  const float* wof   = (const float*)d_in[1];
  const float* bof   = (const float*)d_in[2];
  const float* w     = (const float*)d_in[3];
  const float* bias  = (const float*)d_in[4];
  const float* gamma = (const float*)d_in[5];
  const float* beta  = (const float*)d_in[6];
  const float* mean  = (const float*)d_in[7];
  const float* var   = (const float*)d_in[8];
  float* out = (float*)d_out;
  float* ws  = (float*)d_ws;

  hipLaunchKernelGGL(prep0_k, dim3(288), dim3(256), 0, stream,
                     wof, bias, gamma, beta, mean, var, ws);
  hipLaunchKernelGGL(mid_k, dim3(3360), dim3(256), 0, stream,
                     x, w, gamma, var, ws);
  hipLaunchKernelGGL(deform_gemm_f16b, dim3(256), dim3(512), 0, stream,
                     ws, bof, out);
}